// Round 8
// baseline (471.005 us; speedup 1.0000x reference)
//
#include <hip/hip_runtime.h>
#include <math.h>

#define NHQ 32
#define NKV 8
#define HD 64
#define QKV_DIM 3072   // (32 + 2*8) * 64
#define MODEL_DIM 2048
#define QSCALE 0.1803368801111204f   // 0.125 * log2(e): folds attn scale + exp2 conversion

typedef __attribute__((ext_vector_type(4))) float     f32x4;
typedef __attribute__((ext_vector_type(8))) _Float16  half8;
typedef __attribute__((ext_vector_type(4))) _Float16  half4v;
typedef __attribute__((ext_vector_type(2))) __fp16    fp16x2;

#define ASYNC_COPY16(g, l)                                                        \
    __builtin_amdgcn_global_load_lds(                                             \
        (const __attribute__((address_space(1))) void*)(g),                       \
        (__attribute__((address_space(3))) void*)(l), 16, 0, 0)

__device__ __forceinline__ float fast_exp2(float x)
{
#if __has_builtin(__builtin_amdgcn_exp2f)
    return __builtin_amdgcn_exp2f(x);
#else
    float r;
    asm volatile("v_exp_f32 %0, %1\ns_nop 0" : "=v"(r) : "v"(x));
    return r;
#endif
}

// ---------------------------------------------------------------------------
// Fused setup: three fp32->f16 converts + RoPE sincos table in ONE launch.
// ---------------------------------------------------------------------------
__global__ __launch_bounds__(256)
void setup_kernel(const float* __restrict__ ha, const float* __restrict__ hb,
                  const float* __restrict__ hc, _Float16* __restrict__ da,
                  _Float16* __restrict__ db, _Float16* __restrict__ dc,
                  const int* __restrict__ pos, float* __restrict__ tab,
                  int n4a, int n4b, int n4c, int S)
{
    int i = blockIdx.x * 256 + threadIdx.x;
    if (i < n4a + n4b + n4c) {
        const float* src; _Float16* dst; int j;
        if (i < n4a)            { src = ha; dst = da; j = i; }
        else if (i < n4a + n4b) { src = hb; dst = db; j = i - n4a; }
        else                    { src = hc; dst = dc; j = i - n4a - n4b; }
        float4 v = ((const float4*)src)[j];
        half4v h = { (_Float16)v.x, (_Float16)v.y, (_Float16)v.z, (_Float16)v.w };
        ((half4v*)dst)[j] = h;
    } else {
        int k = i - (n4a + n4b + n4c);
        if (k < S * 32) {
            int s = k >> 5, fi = k & 31;
            float p = (float)pos[s];
            float inv_freq = powf(150000.0f, -(float)fi * (1.0f / 32.0f));
            float ang = p * inv_freq;
            tab[s * 64 + fi]      = cosf(ang);
            tab[s * 64 + 32 + fi] = sinf(ang);
        }
    }
}

// ---------------------------------------------------------------------------
// f16 MFMA GEMM: C[M,N] = A[M,K] @ W[N,K]^T + bias[N]
// MODE 0: fp32 out. MODE 2: f16 out + fused RoPE epilogue.
// ---------------------------------------------------------------------------
template<int MODE>
__global__ __launch_bounds__(256)
void gemm_f16_mfma(const _Float16* __restrict__ A, const _Float16* __restrict__ W,
                   const float* __restrict__ bias, void* __restrict__ Cout,
                   const float* __restrict__ tab, int M, int N, int K, int S)
{
    __shared__ _Float16 As[128 * 32];
    __shared__ _Float16 Bs[128 * 32];

    const int t    = threadIdx.x;
    const int w    = t >> 6;
    const int lane = t & 63;
    const int quad = lane >> 4, l15 = lane & 15;
    const size_t m0 = (size_t)blockIdx.y * 128;
    const size_t n0 = (size_t)blockIdx.x * 128;
    const int wm = (w >> 1) * 64, wn = (w & 1) * 64;

    const int row0 = t >> 2;
    const int sub  = (t & 3) * 8;
    const _Float16* ag0 = A + (m0 + row0) * K + sub;
    const _Float16* ag1 = A + (m0 + 64 + row0) * K + sub;
    const _Float16* bg0 = W + (n0 + row0) * K + sub;
    const _Float16* bg1 = W + (n0 + 64 + row0) * K + sub;
    _Float16* al0 = &As[w * 512];
    _Float16* al1 = &As[2048 + w * 512];
    _Float16* bl0 = &Bs[w * 512];
    _Float16* bl1 = &Bs[2048 + w * 512];

    f32x4 acc[4][4];
#pragma unroll
    for (int i = 0; i < 4; i++)
#pragma unroll
        for (int j = 0; j < 4; j++) acc[i][j] = (f32x4){0.f, 0.f, 0.f, 0.f};

    for (int k0 = 0; k0 < K; k0 += 32) {
        ASYNC_COPY16(ag0 + k0, al0);
        ASYNC_COPY16(ag1 + k0, al1);
        ASYNC_COPY16(bg0 + k0, bl0);
        ASYNC_COPY16(bg1 + k0, bl1);
        __syncthreads();

        half8 af[4], bf[4];
#pragma unroll
        for (int i = 0; i < 4; i++) {
            af[i] = *(const half8*)&As[(wm + i * 16 + l15) * 32 + quad * 8];
            bf[i] = *(const half8*)&Bs[(wn + i * 16 + l15) * 32 + quad * 8];
        }
#pragma unroll
        for (int i = 0; i < 4; i++)
#pragma unroll
            for (int j = 0; j < 4; j++)
                acc[i][j] = __builtin_amdgcn_mfma_f32_16x16x32_f16(af[i], bf[j], acc[i][j], 0, 0, 0);
        __syncthreads();
    }

    float bv[4];
#pragma unroll
    for (int j = 0; j < 4; j++) bv[j] = bias[n0 + wn + j * 16 + l15];

    const int ct = (int)(((n0 + wn) >> 6) % 6);

#pragma unroll
    for (int i = 0; i < 4; i++)
#pragma unroll
        for (int r = 0; r < 4; r++) {
            const size_t row = m0 + wm + i * 16 + quad * 4 + r;
            float v[4];
#pragma unroll
            for (int j = 0; j < 4; j++) v[j] = acc[i][j][r] + bv[j];

            if (MODE == 2 && ct != 5) {
                const float* tc = tab + (size_t)(row % S) * 64;
                const float ca = tc[l15],      sa = tc[32 + l15];
                const float cb = tc[16 + l15], sb = tc[48 + l15];
                const float qs = (ct < 4) ? QSCALE : 1.0f;
                const float n0v = v[0] * ca - v[2] * sa;
                const float n1v = v[1] * cb - v[3] * sb;
                const float n2v = v[2] * ca + v[0] * sa;
                const float n3v = v[3] * cb + v[1] * sb;
                v[0] = n0v * qs; v[1] = n1v * qs; v[2] = n2v * qs; v[3] = n3v * qs;
            }

            const size_t col = n0 + wn + l15;
#pragma unroll
            for (int j = 0; j < 4; j++) {
                if (MODE != 0) ((_Float16*)Cout)[row * N + col + j * 16] = (_Float16)v[j];
                else           ((float*)Cout)[row * N + col + j * 16] = v[j];
            }
        }
}

// ---------------------------------------------------------------------------
// V transpose: qkv V-chunks [token][g-chunk 64] -> vtg[(g*64 + d)*BS + token].
// ---------------------------------------------------------------------------
__global__ __launch_bounds__(256)
void transpose_v_kernel(const _Float16* __restrict__ qkv, _Float16* __restrict__ vtg, int BS)
{
    __shared__ _Float16 tile[64 * 72];
    const int t = threadIdx.x;
    const int tb = blockIdx.x * 64;
    const int g = blockIdx.y;
    const int voff = (g * 6 + 5) * 64;

    const int tok = t >> 2, dsub = (t & 3) * 16;
    const _Float16* src = qkv + (size_t)(tb + tok) * QKV_DIM + voff + dsub;
    *(half8*)&tile[tok * 72 + dsub]     = *(const half8*)(src);
    *(half8*)&tile[tok * 72 + dsub + 8] = *(const half8*)(src + 8);
    __syncthreads();

    const int d = t >> 2, tsub = (t & 3) * 16;
    half8 a, c;
#pragma unroll
    for (int i = 0; i < 8; i++) a[i] = tile[(tsub + i) * 72 + d];
#pragma unroll
    for (int i = 0; i < 8; i++) c[i] = tile[(tsub + 8 + i) * 72 + d];
    _Float16* dst = vtg + ((size_t)g * 64 + d) * BS + tb + tsub;
    *(half8*)dst       = a;
    *(half8*)(dst + 8) = c;
}

// ---------------------------------------------------------------------------
// BARRIER-FREE MFMA flash attention.
// Grid (NKV, S/32, B) -> blockIdx.x = g = XCD id (id%8): each XCD's L2 holds
// only its group's ~1 MB of K/V. 256 threads = 4 waves; wave w = q-head
// g*4+w over 32 q-rows. K frags loaded directly from qkv, V^T frags directly
// from vtg (both wave-uniform working sets, L1/L2-resident) — no staging LDS,
// NO __syncthreads anywhere. Only LDS use: per-wave P transpose (wave-private,
// ordered by lgkmcnt). L = P @ ones via constant ones-fragment: every lane's
// accumulator holds its own row's sum -> shuffle-free epilogue.
// ---------------------------------------------------------------------------
__global__ __launch_bounds__(256)
void attn_mfma(const _Float16* __restrict__ qkv, const _Float16* __restrict__ vtg,
               _Float16* __restrict__ out, int B, int S)
{
    __shared__ _Float16 PsAll[4][32 * 72];   // per-wave P [qrow][key], stride 72

    const int t = threadIdx.x, w = t >> 6, lane = t & 63;
    const int quad = lane >> 4, l15 = lane & 15;
    const int g = blockIdx.x, b = blockIdx.z;
    const int q0 = blockIdx.y * 32;
    const int qoff = (g * 6 + w) * 64;
    const int koff = (g * 6 + 4) * 64;
    const size_t BSz = (size_t)B * S;

    _Float16* Ps = &PsAll[w][0];

    // Q fragments: subtile s covers qrows q0+s*16 .. +16 (B-operand layout)
    half8 qf[2][2];
#pragma unroll
    for (int s = 0; s < 2; s++) {
        const _Float16* qp = qkv + (size_t)(b * S + q0 + s * 16 + l15) * QKV_DIM + qoff;
        qf[s][0] = *(const half8*)(qp + quad * 8);
        qf[s][1] = *(const half8*)(qp + 32 + quad * 8);
    }

    // frag base pointers
    const _Float16* kfb = qkv + (size_t)(b * S + l15) * QKV_DIM + koff + quad * 8;
    const _Float16* vfb = vtg + ((size_t)g * 64 + l15) * BSz + (size_t)b * S + quad * 8;

    const half8 ones = { (_Float16)1.f, (_Float16)1.f, (_Float16)1.f, (_Float16)1.f,
                         (_Float16)1.f, (_Float16)1.f, (_Float16)1.f, (_Float16)1.f };

    f32x4 O[2][4], L[2];
#pragma unroll
    for (int s = 0; s < 2; s++) {
        L[s] = (f32x4){0.f, 0.f, 0.f, 0.f};
#pragma unroll
        for (int dt = 0; dt < 4; dt++) O[s][dt] = (f32x4){0.f, 0.f, 0.f, 0.f};
    }

    for (int kt = 0; kt < S; kt += 64) {
        const _Float16* kp = kfb + (size_t)kt * QKV_DIM;
        const _Float16* vp = vfb + kt;

        // ---- K frags direct from global: A-operand, 16 keys x 32 d each ----
        half8 kf[4][2];
#pragma unroll
        for (int mt = 0; mt < 4; mt++) {
            kf[mt][0] = *(const half8*)(kp + (size_t)(mt * 16) * QKV_DIM);
            kf[mt][1] = *(const half8*)(kp + (size_t)(mt * 16) * QKV_DIM + 32);
        }
        // ---- V^T frags direct from global (independent; in flight during QK/exp)
        half8 vv[4][2];
#pragma unroll
        for (int dt = 0; dt < 4; dt++) {
            vv[dt][0] = *(const half8*)(vp + (size_t)(dt * 16) * BSz);
            vv[dt][1] = *(const half8*)(vp + (size_t)(dt * 16) * BSz + 32);
        }

        // ---- per subtile: S^T = K.Q^T -> exp2 -> Ps ----
#pragma unroll
        for (int s = 0; s < 2; s++) {
            f32x4 sacc[4];
#pragma unroll
            for (int mt = 0; mt < 4; mt++) {
                f32x4 z = (f32x4){0.f, 0.f, 0.f, 0.f};
                z = __builtin_amdgcn_mfma_f32_16x16x32_f16(kf[mt][0], qf[s][0], z, 0, 0, 0);
                z = __builtin_amdgcn_mfma_f32_16x16x32_f16(kf[mt][1], qf[s][1], z, 0, 0, 0);
                sacc[mt] = z;
            }
#pragma unroll
            for (int mt = 0; mt < 4; mt++) {
                fp16x2 pa = __builtin_amdgcn_cvt_pkrtz(fast_exp2(sacc[mt][0]),
                                                       fast_exp2(sacc[mt][1]));
                fp16x2 pb = __builtin_amdgcn_cvt_pkrtz(fast_exp2(sacc[mt][2]),
                                                       fast_exp2(sacc[mt][3]));
                uint2 u;
                u.x = __builtin_bit_cast(unsigned int, pa);
                u.y = __builtin_bit_cast(unsigned int, pb);
                *(uint2*)&Ps[(s * 16 + l15) * 72 + mt * 16 + quad * 4] = u;
            }
        }
        asm volatile("s_waitcnt lgkmcnt(0)" ::: "memory");   // own-wave P visible

        // ---- P frags (A-operand) from own-wave LDS ----
        half8 pf[2][2];
#pragma unroll
        for (int s = 0; s < 2; s++) {
            pf[s][0] = *(const half8*)&Ps[(s * 16 + l15) * 72 + quad * 8];
            pf[s][1] = *(const half8*)&Ps[(s * 16 + l15) * 72 + 32 + quad * 8];
        }

        // ---- PV: O += P.V ; L += P.ones (every lane gets its row's sum) ----
#pragma unroll
        for (int dt = 0; dt < 4; dt++)
#pragma unroll
            for (int s = 0; s < 2; s++) {
                O[s][dt] = __builtin_amdgcn_mfma_f32_16x16x32_f16(pf[s][0], vv[dt][0], O[s][dt], 0, 0, 0);
                O[s][dt] = __builtin_amdgcn_mfma_f32_16x16x32_f16(pf[s][1], vv[dt][1], O[s][dt], 0, 0, 0);
            }
#pragma unroll
        for (int s = 0; s < 2; s++) {
            L[s] = __builtin_amdgcn_mfma_f32_16x16x32_f16(pf[s][0], ones, L[s], 0, 0, 0);
            L[s] = __builtin_amdgcn_mfma_f32_16x16x32_f16(pf[s][1], ones, L[s], 0, 0, 0);
        }
    }

    // ---- epilogue: O row (quad*4+r) matches L[s][r] in the same lane ----
    const int hq = g * 4 + w;
#pragma unroll
    for (int s = 0; s < 2; s++)
#pragma unroll
        for (int r = 0; r < 4; r++) {
            const float ir = 1.0f / L[s][r];
            const size_t row = (size_t)(b * S + q0 + s * 16 + quad * 4 + r);
#pragma unroll
            for (int dt = 0; dt < 4; dt++)
                out[row * (NHQ * HD) + hq * 64 + dt * 16 + l15] = (_Float16)(O[s][dt][r] * ir);
        }
}

// ---------------------------------------------------------------------------
extern "C" void kernel_launch(void* const* d_in, const int* in_sizes, int n_in,
                              void* d_out, int out_size, void* d_ws, size_t ws_size,
                              hipStream_t stream)
{
    const float* hidden = (const float*)d_in[0];
    const int*   pos    = (const int*)d_in[1];
    const float* qkv_w  = (const float*)d_in[2];
    const float* qkv_b  = (const float*)d_in[3];
    const float* o_w    = (const float*)d_in[4];
    const float* o_b    = (const float*)d_in[5];
    float* out = (float*)d_out;

    const int S  = in_sizes[1];                 // 2048
    const int BS = in_sizes[0] / MODEL_DIM;     // 4096
    const int B  = BS / S;                      // 2

    _Float16* hA   = (_Float16*)d_ws;                      // [BS, 2048]
    _Float16* hW1  = hA   + (size_t)BS * MODEL_DIM;        // [3072, 2048]
    _Float16* hW2  = hW1  + (size_t)QKV_DIM * MODEL_DIM;   // [2048, 2048]
    _Float16* qkvh = hW2  + (size_t)MODEL_DIM * MODEL_DIM; // [BS, 3072]
    _Float16* atth = qkvh + (size_t)BS * QKV_DIM;          // [BS, 2048]
    float*    tab  = (float*)(atth + (size_t)BS * MODEL_DIM); // [S, 64]
    _Float16* vtg  = (_Float16*)(tab + (size_t)S * 64);    // [NKV*64, BS]

    const int n4a = BS * MODEL_DIM / 4;
    const int n4b = QKV_DIM * MODEL_DIM / 4;
    const int n4c = MODEL_DIM * MODEL_DIM / 4;
    const int setup_items = n4a + n4b + n4c + S * 32;

    // 0) fused converts + rope table (one launch)
    setup_kernel<<<(setup_items + 255) / 256, 256, 0, stream>>>(
        hidden, qkv_w, o_w, hA, hW1, hW2, pos, tab, n4a, n4b, n4c, S);

    // 1) QKV projection with fused RoPE (+0.125*log2e on Q)
    gemm_f16_mfma<2><<<dim3(QKV_DIM / 128, BS / 128), 256, 0, stream>>>(
        hA, hW1, qkv_b, qkvh, tab, BS, QKV_DIM, MODEL_DIM, S);

    // 1b) V transpose -> vtg
    transpose_v_kernel<<<dim3(BS / 64, NKV), 256, 0, stream>>>(qkvh, vtg, BS);

    // 2) Attention -> atth [BS, 2048]; blockIdx.x = g -> XCD-locality for K/V
    attn_mfma<<<dim3(NKV, S / 32, B), 256, 0, stream>>>(qkvh, vtg, atth, B, S);

    // 3) Output projection (fp32 out)
    gemm_f16_mfma<0><<<dim3(MODEL_DIM / 128, BS / 128), 256, 0, stream>>>(
        atth, hW2, o_b, out, nullptr, BS, MODEL_DIM, MODEL_DIM, S);
}